// Round 1
// baseline (2556.970 us; speedup 1.0000x reference)
//
#include <hip/hip_runtime.h>
#include <math.h>

#define NN   50000
#define EE   800000
#define IND  128
#define EDD  16
#define HIDD 32
#define NH   4
#define HC   128     // NH*HIDD
#define OUTD 64
#define NEG  0.1f
#define BN_EPS 1e-5f

__device__ __forceinline__ float lrelu(float x) { return x >= 0.f ? x : NEG * x; }

// ---------------- CSR build ----------------
__global__ void count_kernel(const int* ei, int* cnt) {
    int e = blockIdx.x * blockDim.x + threadIdx.x;
    if (e >= EE) return;
    atomicAdd(&cnt[ei[EE + e]], 1);
}

// single-block exclusive scan of (cnt[i]+1), rowstart[NN] = total
__global__ void scan_kernel(const int* cnt, int* rowstart) {
    __shared__ int sh[1024];
    __shared__ int carry_s;
    int tid = threadIdx.x;
    if (tid == 0) carry_s = 0;
    __syncthreads();
    for (int base = 0; base < NN; base += 1024) {
        int i = base + tid;
        int v = (i < NN) ? (cnt[i] + 1) : 0;
        sh[tid] = v;
        __syncthreads();
        for (int off = 1; off < 1024; off <<= 1) {
            int add = (tid >= off) ? sh[tid - off] : 0;
            __syncthreads();
            sh[tid] += add;
            __syncthreads();
        }
        int incl  = sh[tid];
        int total = sh[1023];
        int carry = carry_s;
        if (i < NN) rowstart[i] = carry + incl - v;
        __syncthreads();
        if (tid == 0) carry_s = carry + total;
        __syncthreads();
    }
    if (threadIdx.x == 0) rowstart[NN] = carry_s;
}

__global__ void scatter_kernel(const int* ei, const int* rowstart, int* cursor, int* csr) {
    int e = blockIdx.x * blockDim.x + threadIdx.x;
    if (e >= EE) return;
    int d = ei[EE + e];
    int pos = rowstart[d] + atomicAdd(&cursor[d], 1);
    csr[pos] = e;
}

__global__ void selfloop_kernel(const int* rowstart, const int* cnt, int* csr) {
    int n = blockIdx.x * blockDim.x + threadIdx.x;
    if (n >= NN) return;
    csr[rowstart[n] + cnt[n]] = EE + n;   // last slot of node n's segment
}

// ---------------- self-loop edge_attr (mean of incoming) ----------------
__global__ void loopsum_kernel(const int* ei, const float* eattr, float* loop_sum) {
    int t = blockIdx.x * blockDim.x + threadIdx.x;
    if (t >= EE * EDD) return;
    int e = t >> 4, k = t & 15;
    atomicAdd(&loop_sum[ei[EE + e] * EDD + k], eattr[t]);
}

__global__ void loopdiv_kernel(float* loop_sum, const int* cnt) {
    int t = blockIdx.x * blockDim.x + threadIdx.x;
    if (t >= NN * EDD) return;
    int c = cnt[t >> 4];
    loop_sum[t] *= 1.0f / (float)(c > 0 ? c : 1);
}

// ---------------- input embed: Linear(128->32)+BN(eval)+LeakyReLU ----------------
__global__ void embed_kernel(const float* x, const float* W0, const float* b0,
                             const float* g, const float* bb, const float* bm,
                             const float* bv, float* out) {
    int tid = threadIdx.x;
    int c = tid & 31, r = tid >> 5;           // 8 rows x 32 cols per block
    int n0 = blockIdx.x * 8;
    __shared__ float sx[8][IND];
    for (int i = tid; i < 8 * IND; i += 256) sx[i >> 7][i & 127] = x[(size_t)n0 * IND + i];
    __syncthreads();
    float acc = b0[c];
    const float* wr = W0 + c * IND;
    #pragma unroll 8
    for (int k = 0; k < IND; k++) acc += sx[r][k] * wr[k];
    float bn = (acc - bm[c]) * (1.0f / sqrtf(bv[c] + BN_EPS)) * g[c] + bb[c];
    out[(size_t)(n0 + r) * HIDD + c] = lrelu(bn);
}

// ---------------- per-layer linear: xl = f@Wl.T+bl, xr = f@Wr.T+br ----------------
__global__ void lin_kernel(const float* f, const float* Wl, const float* bl,
                           const float* Wr, const float* br, float* xl, float* xr) {
    int j = threadIdx.x;                       // 0..255
    int n0 = blockIdx.x * 4;                   // 4 nodes per block
    const float* W = (j < HC) ? Wl : Wr;
    const float* b = (j < HC) ? bl : br;
    float*       o = (j < HC) ? xl : xr;
    int c = j & (HC - 1);
    __shared__ float sf[4][HIDD];
    if (threadIdx.x < 128) sf[threadIdx.x >> 5][threadIdx.x & 31] =
        f[(size_t)(n0 + (threadIdx.x >> 5)) * HIDD + (threadIdx.x & 31)];
    __syncthreads();
    float bc = b[c];
    float a0 = bc, a1 = bc, a2 = bc, a3 = bc;
    const float* wr = W + c * HIDD;
    #pragma unroll
    for (int k = 0; k < HIDD; k++) {
        float w = wr[k];
        a0 += sf[0][k] * w; a1 += sf[1][k] * w;
        a2 += sf[2][k] * w; a3 += sf[3][k] * w;
    }
    o[(size_t)(n0 + 0) * HC + c] = a0;
    o[(size_t)(n0 + 1) * HC + c] = a1;
    o[(size_t)(n0 + 2) * HC + c] = a2;
    o[(size_t)(n0 + 3) * HC + c] = a3;
}

// ---------------- edge scoring: alpha[e][h] ----------------
// one wave per edge; lane owns channels (2*lane, 2*lane+1)
__global__ void alpha_kernel(const float* xl, const float* xr, const int* ei,
                             const float* eattr, const float* loop_attr,
                             const float* We, const float* att, float* alpha) {
    int gid = blockIdx.x * blockDim.x + threadIdx.x;
    int e = gid >> 6;
    int lane = threadIdx.x & 63;
    const int Et = EE + NN;
    if (e >= Et) return;
    int s, d;
    const float* ea;
    if (e < EE) { s = ei[e]; d = ei[EE + e]; ea = eattr + (size_t)e * EDD; }
    else        { s = e - EE; d = s;         ea = loop_attr + (size_t)(e - EE) * EDD; }

    float ev = (lane < EDD) ? ea[lane] : 0.f;

    int c0 = lane * 2;
    float2 xlv = *(const float2*)(xl + (size_t)s * HC + c0);
    float2 xrv = *(const float2*)(xr + (size_t)d * HC + c0);

    float ea0 = 0.f, ea1 = 0.f;
    const float* w0 = We + c0 * EDD;
    const float* w1 = We + (c0 + 1) * EDD;
    #pragma unroll
    for (int k = 0; k < EDD; k++) {
        float ek = __shfl(ev, k);
        ea0 += w0[k] * ek;
        ea1 += w1[k] * ek;
    }
    float m0 = lrelu(xlv.x + xrv.x + ea0);
    float m1 = lrelu(xlv.y + xrv.y + ea1);
    float p = m0 * att[c0] + m1 * att[c0 + 1];
    #pragma unroll
    for (int off = 1; off < 16; off <<= 1) p += __shfl_xor(p, off);
    if ((lane & 15) == 0) alpha[(size_t)e * NH + (lane >> 4)] = p;
}

// ---------------- per-node softmax + aggregate + heads-mean + bias ----------------
// one wave per node
__global__ void agg_kernel(const float* xl, const float* alpha, const int* rowstart,
                           const int* csr, const int* ei, const float* bias, float* out) {
    int n = (blockIdx.x * blockDim.x + threadIdx.x) >> 6;
    int lane = threadIdx.x & 63;
    if (n >= NN) return;
    int start = rowstart[n], deg = rowstart[n + 1] - start;

    // pass 1: per-head max
    float4 mx = make_float4(-INFINITY, -INFINITY, -INFINITY, -INFINITY);
    for (int i = lane; i < deg; i += 64) {
        int e = csr[start + i];
        float4 a = *(const float4*)(alpha + (size_t)e * NH);
        mx.x = fmaxf(mx.x, a.x); mx.y = fmaxf(mx.y, a.y);
        mx.z = fmaxf(mx.z, a.z); mx.w = fmaxf(mx.w, a.w);
    }
    #pragma unroll
    for (int off = 1; off < 64; off <<= 1) {
        mx.x = fmaxf(mx.x, __shfl_xor(mx.x, off));
        mx.y = fmaxf(mx.y, __shfl_xor(mx.y, off));
        mx.z = fmaxf(mx.z, __shfl_xor(mx.z, off));
        mx.w = fmaxf(mx.w, __shfl_xor(mx.w, off));
    }
    // pass 2: per-head sum of exp
    float4 sm = make_float4(0.f, 0.f, 0.f, 0.f);
    for (int i = lane; i < deg; i += 64) {
        int e = csr[start + i];
        float4 a = *(const float4*)(alpha + (size_t)e * NH);
        sm.x += __expf(a.x - mx.x); sm.y += __expf(a.y - mx.y);
        sm.z += __expf(a.z - mx.z); sm.w += __expf(a.w - mx.w);
    }
    #pragma unroll
    for (int off = 1; off < 64; off <<= 1) {
        sm.x += __shfl_xor(sm.x, off); sm.y += __shfl_xor(sm.y, off);
        sm.z += __shfl_xor(sm.z, off); sm.w += __shfl_xor(sm.w, off);
    }
    // pass 3: weighted aggregate; lane owns channels (2*lane, 2*lane+1), head = lane>>4
    int c0 = 2 * lane;
    int h = lane >> 4;
    float am = (h == 0) ? mx.x : (h == 1) ? mx.y : (h == 2) ? mx.z : mx.w;
    float dn = (h == 0) ? sm.x : (h == 1) ? sm.y : (h == 2) ? sm.z : sm.w;
    float inv_dn = 1.0f / dn;
    float acc0 = 0.f, acc1 = 0.f;
    for (int i = 0; i < deg; i++) {
        int e = csr[start + i];
        float a = alpha[(size_t)e * NH + h];
        float w = __expf(a - am) * inv_dn;
        int s;
        if (e < EE) s = ei[e]; else s = e - EE;
        float2 xv = *(const float2*)(xl + (size_t)s * HC + c0);
        acc0 += xv.x * w;
        acc1 += xv.y * w;
    }
    // heads-mean: sum lanes {l, l^16, l^32, l^48}
    acc0 += __shfl_xor(acc0, 16); acc0 += __shfl_xor(acc0, 32);
    acc1 += __shfl_xor(acc1, 16); acc1 += __shfl_xor(acc1, 32);
    if (lane < 16) {
        out[(size_t)n * HIDD + 2 * lane]     = acc0 * 0.25f + bias[2 * lane];
        out[(size_t)n * HIDD + 2 * lane + 1] = acc1 * 0.25f + bias[2 * lane + 1];
    }
}

// ---------------- output head: LeakyReLU(h @ Wout.T + bout) ----------------
__global__ void out_kernel(const float* h, const float* Wout, const float* bout, float* out) {
    int tid = blockIdx.x * blockDim.x + threadIdx.x;
    int n = tid >> 6, c = tid & 63;
    if (n >= NN) return;
    float acc = bout[c];
    const float* hr = h + (size_t)n * HIDD;
    const float* wr = Wout + c * HIDD;
    #pragma unroll
    for (int k = 0; k < HIDD; k++) acc += hr[k] * wr[k];
    out[tid] = lrelu(acc);
}

extern "C" void kernel_launch(void* const* d_in, const int* in_sizes, int n_in,
                              void* d_out, int out_size, void* d_ws, size_t ws_size,
                              hipStream_t stream) {
    const float* x     = (const float*)d_in[0];
    const int*   ei    = (const int*)  d_in[1];
    const float* eattr = (const float*)d_in[2];
    const float* W0    = (const float*)d_in[3];
    const float* b0    = (const float*)d_in[4];
    const float* bn_g  = (const float*)d_in[5];
    const float* bn_b  = (const float*)d_in[6];
    const float* bn_m  = (const float*)d_in[7];
    const float* bn_v  = (const float*)d_in[8];
    const float* Wl[2]   = { (const float*)d_in[9],  (const float*)d_in[16] };
    const float* bl[2]   = { (const float*)d_in[10], (const float*)d_in[17] };
    const float* Wr[2]   = { (const float*)d_in[11], (const float*)d_in[18] };
    const float* br[2]   = { (const float*)d_in[12], (const float*)d_in[19] };
    const float* We[2]   = { (const float*)d_in[13], (const float*)d_in[20] };
    const float* att[2]  = { (const float*)d_in[14], (const float*)d_in[21] };
    const float* bias[2] = { (const float*)d_in[15], (const float*)d_in[22] };
    const float* Wout  = (const float*)d_in[23];
    const float* bout  = (const float*)d_in[24];
    float* out = (float*)d_out;

    const int Et = EE + NN;
    // workspace carve-up (all 256B aligned)
    char* p = (char*)d_ws;
    auto carve = [&](size_t bytes) { char* r = p; p += (bytes + 255) & ~(size_t)255; return r; };
    float* e_feat    = (float*)carve((size_t)NN * HIDD * 4);   // embed out / layer2 out
    float* h1        = (float*)carve((size_t)NN * HIDD * 4);   // layer1 out
    float* xl        = (float*)carve((size_t)NN * HC * 4);
    float* xr        = (float*)carve((size_t)NN * HC * 4);
    float* alpha     = (float*)carve((size_t)Et * NH * 4);
    float* loop_attr = (float*)carve((size_t)NN * EDD * 4);
    int*   cnt       = (int*)  carve((size_t)NN * 4);
    int*   rowstart  = (int*)  carve((size_t)(NN + 1) * 4);
    int*   cursor    = (int*)  carve((size_t)NN * 4);
    int*   csr       = (int*)  carve((size_t)Et * 4);

    hipMemsetAsync(cnt, 0, (size_t)NN * 4, stream);
    hipMemsetAsync(cursor, 0, (size_t)NN * 4, stream);
    hipMemsetAsync(loop_attr, 0, (size_t)NN * EDD * 4, stream);

    count_kernel<<<(EE + 255) / 256, 256, 0, stream>>>(ei, cnt);
    loopsum_kernel<<<(EE * EDD + 255) / 256, 256, 0, stream>>>(ei, eattr, loop_attr);
    scan_kernel<<<1, 1024, 0, stream>>>(cnt, rowstart);
    loopdiv_kernel<<<(NN * EDD + 255) / 256, 256, 0, stream>>>(loop_attr, cnt);
    scatter_kernel<<<(EE + 255) / 256, 256, 0, stream>>>(ei, rowstart, cursor, csr);
    selfloop_kernel<<<(NN + 255) / 256, 256, 0, stream>>>(rowstart, cnt, csr);

    embed_kernel<<<NN / 8, 256, 0, stream>>>(x, W0, b0, bn_g, bn_b, bn_m, bn_v, e_feat);

    const float* fin[2] = { e_feat, h1 };
    float* fout[2] = { h1, e_feat };   // reuse e_feat as layer-2 output
    for (int l = 0; l < 2; l++) {
        lin_kernel<<<NN / 4, 256, 0, stream>>>(fin[l], Wl[l], bl[l], Wr[l], br[l], xl, xr);
        alpha_kernel<<<((size_t)Et * 64 + 255) / 256, 256, 0, stream>>>(
            xl, xr, ei, eattr, loop_attr, We[l], att[l], alpha);
        agg_kernel<<<((size_t)NN * 64 + 255) / 256, 256, 0, stream>>>(
            xl, alpha, rowstart, csr, ei, bias[l], fout[l]);
    }
    out_kernel<<<(NN * 64 + 255) / 256, 256, 0, stream>>>(e_feat, Wout, bout, out);
}

// Round 2
// 1259.689 us; speedup vs baseline: 2.0298x; 2.0298x over previous
//
#include <hip/hip_runtime.h>
#include <math.h>

#define NN   50000
#define EE   800000
#define IND  128
#define EDD  16
#define HIDD 32
#define NH   4
#define HC   128     // NH*HIDD
#define OUTD 64
#define NEG  0.1f
#define BN_EPS 1e-5f

__device__ __forceinline__ float lrelu(float x) { return x >= 0.f ? x : NEG * x; }

// ---------------- CSR build ----------------
__global__ void count_kernel(const int* ei, int* cnt) {
    int e = blockIdx.x * blockDim.x + threadIdx.x;
    if (e >= EE) return;
    atomicAdd(&cnt[ei[EE + e]], 1);
}

// single-block exclusive scan of (cnt[i]+1), rowstart[NN] = total
__global__ void scan_kernel(const int* cnt, int* rowstart) {
    __shared__ int sh[1024];
    __shared__ int carry_s;
    int tid = threadIdx.x;
    if (tid == 0) carry_s = 0;
    __syncthreads();
    for (int base = 0; base < NN; base += 1024) {
        int i = base + tid;
        int v = (i < NN) ? (cnt[i] + 1) : 0;
        sh[tid] = v;
        __syncthreads();
        for (int off = 1; off < 1024; off <<= 1) {
            int add = (tid >= off) ? sh[tid - off] : 0;
            __syncthreads();
            sh[tid] += add;
            __syncthreads();
        }
        int incl  = sh[tid];
        int total = sh[1023];
        int carry = carry_s;
        if (i < NN) rowstart[i] = carry + incl - v;
        __syncthreads();
        if (tid == 0) carry_s = carry + total;
        __syncthreads();
    }
    if (threadIdx.x == 0) rowstart[NN] = carry_s;
}

// store BOTH edge id and src id — removes one level of the dependent-load chain
__global__ void scatter_kernel(const int* ei, const int* rowstart, int* cursor,
                               int* csr_e, int* csr_src) {
    int e = blockIdx.x * blockDim.x + threadIdx.x;
    if (e >= EE) return;
    int d = ei[EE + e];
    int pos = rowstart[d] + atomicAdd(&cursor[d], 1);
    csr_e[pos]   = e;
    csr_src[pos] = ei[e];
}

__global__ void selfloop_kernel(const int* rowstart, const int* cnt, int* csr_e, int* csr_src) {
    int n = blockIdx.x * blockDim.x + threadIdx.x;
    if (n >= NN) return;
    int pos = rowstart[n] + cnt[n];      // last slot of node n's segment
    csr_e[pos]   = EE + n;
    csr_src[pos] = n;
}

// ---------------- self-loop edge_attr (mean of incoming) ----------------
__global__ void loopsum_kernel(const int* ei, const float* eattr, float* loop_sum) {
    int t = blockIdx.x * blockDim.x + threadIdx.x;
    if (t >= EE * EDD) return;
    int e = t >> 4, k = t & 15;
    atomicAdd(&loop_sum[ei[EE + e] * EDD + k], eattr[t]);
}

__global__ void loopdiv_kernel(float* loop_sum, const int* cnt) {
    int t = blockIdx.x * blockDim.x + threadIdx.x;
    if (t >= NN * EDD) return;
    int c = cnt[t >> 4];
    loop_sum[t] *= 1.0f / (float)(c > 0 ? c : 1);
}

// ---------------- input embed: Linear(128->32)+BN(eval)+LeakyReLU ----------------
__global__ void embed_kernel(const float* x, const float* W0, const float* b0,
                             const float* g, const float* bb, const float* bm,
                             const float* bv, float* out) {
    int tid = threadIdx.x;
    int c = tid & 31, r = tid >> 5;           // 8 rows x 32 cols per block
    int n0 = blockIdx.x * 8;
    __shared__ float sx[8][IND];
    for (int i = tid; i < 8 * IND; i += 256) sx[i >> 7][i & 127] = x[(size_t)n0 * IND + i];
    __syncthreads();
    float acc = b0[c];
    const float* wr = W0 + c * IND;
    #pragma unroll 8
    for (int k = 0; k < IND; k++) acc += sx[r][k] * wr[k];
    float bn = (acc - bm[c]) * (1.0f / sqrtf(bv[c] + BN_EPS)) * g[c] + bb[c];
    out[(size_t)(n0 + r) * HIDD + c] = lrelu(bn);
}

// ---------------- per-layer linear: xl = f@Wl.T+bl, xr = f@Wr.T+br ----------------
__global__ void lin_kernel(const float* f, const float* Wl, const float* bl,
                           const float* Wr, const float* br, float* xl, float* xr) {
    int j = threadIdx.x;                       // 0..255
    int n0 = blockIdx.x * 4;                   // 4 nodes per block
    const float* W = (j < HC) ? Wl : Wr;
    const float* b = (j < HC) ? bl : br;
    float*       o = (j < HC) ? xl : xr;
    int c = j & (HC - 1);
    __shared__ float sf[4][HIDD];
    if (threadIdx.x < 128) sf[threadIdx.x >> 5][threadIdx.x & 31] =
        f[(size_t)(n0 + (threadIdx.x >> 5)) * HIDD + (threadIdx.x & 31)];
    __syncthreads();
    float bc = b[c];
    float a0 = bc, a1 = bc, a2 = bc, a3 = bc;
    const float* wr = W + c * HIDD;
    #pragma unroll
    for (int k = 0; k < HIDD; k++) {
        float w = wr[k];
        a0 += sf[0][k] * w; a1 += sf[1][k] * w;
        a2 += sf[2][k] * w; a3 += sf[3][k] * w;
    }
    o[(size_t)(n0 + 0) * HC + c] = a0;
    o[(size_t)(n0 + 1) * HC + c] = a1;
    o[(size_t)(n0 + 2) * HC + c] = a2;
    o[(size_t)(n0 + 3) * HC + c] = a3;
}

// ---------------- fused: edge scoring + online softmax + aggregate ----------------
// one wave per dst node; lane owns channels (2*lane, 2*lane+1); head = lane>>4
__global__ void gat_fused_kernel(const float* xl, const float* xr,
                                 const float* eattr, const float* loop_attr,
                                 const float* We, const float* att,
                                 const int* rowstart, const int* csr_e, const int* csr_src,
                                 const float* bias, float* out) {
    int n = (blockIdx.x * blockDim.x + threadIdx.x) >> 6;
    int lane = threadIdx.x & 63;
    if (n >= NN) return;
    int start = rowstart[n], end = rowstart[n + 1];
    int c0 = 2 * lane;

    float2 xrv = *(const float2*)(xr + (size_t)n * HC + c0);
    float att0 = att[c0], att1 = att[c0 + 1];
    float w0[EDD], w1[EDD];
    #pragma unroll
    for (int k = 0; k < EDD; k++) { w0[k] = We[c0 * EDD + k]; w1[k] = We[(c0 + 1) * EDD + k]; }

    float mh = -INFINITY, lh = 0.f;
    float acc0 = 0.f, acc1 = 0.f;

    // 2-deep software pipeline over the edge list (deg >= 1 always: self loop)
    int eA = csr_e[start];
    int sA = csr_src[start];
    float2 xA = *(const float2*)(xl + (size_t)sA * HC + c0);
    const float* eaA = (eA < EE) ? (eattr + (size_t)eA * EDD)
                                 : (loop_attr + (size_t)(eA - EE) * EDD);
    float evA = (lane < EDD) ? eaA[lane] : 0.f;

    for (int i = start; i < end; i++) {
        float2 xB = make_float2(0.f, 0.f);
        float evB = 0.f;
        if (i + 1 < end) {
            int eB = csr_e[i + 1];
            int sB = csr_src[i + 1];
            xB = *(const float2*)(xl + (size_t)sB * HC + c0);
            const float* eaB = (eB < EE) ? (eattr + (size_t)eB * EDD)
                                         : (loop_attr + (size_t)(eB - EE) * EDD);
            evB = (lane < EDD) ? eaB[lane] : 0.f;
        }
        // ---- compute on edge A ----
        float ea0 = 0.f, ea1 = 0.f;
        #pragma unroll
        for (int k = 0; k < EDD; k++) {
            float ek = __shfl(evA, k);
            ea0 += w0[k] * ek;
            ea1 += w1[k] * ek;
        }
        float m0 = lrelu(xA.x + xrv.x + ea0);
        float m1 = lrelu(xA.y + xrv.y + ea1);
        float p = m0 * att0 + m1 * att1;
        p += __shfl_xor(p, 1); p += __shfl_xor(p, 2);
        p += __shfl_xor(p, 4); p += __shfl_xor(p, 8);   // per-head logit, uniform in 16-lane group
        // online softmax update
        float newm = fmaxf(mh, p);
        float scale = __expf(mh - newm);                // first iter: exp(-inf) = 0
        float w = __expf(p - newm);
        lh = lh * scale + w;
        acc0 = acc0 * scale + w * xA.x;
        acc1 = acc1 * scale + w * xA.y;
        mh = newm;
        // rotate pipeline
        xA = xB; evA = evB;
    }
    float inv = 1.0f / lh;
    acc0 *= inv; acc1 *= inv;
    // heads-mean: sum lanes {l, l^16, l^32, l^48}
    acc0 += __shfl_xor(acc0, 16); acc0 += __shfl_xor(acc0, 32);
    acc1 += __shfl_xor(acc1, 16); acc1 += __shfl_xor(acc1, 32);
    if (lane < 16) {
        out[(size_t)n * HIDD + 2 * lane]     = acc0 * 0.25f + bias[2 * lane];
        out[(size_t)n * HIDD + 2 * lane + 1] = acc1 * 0.25f + bias[2 * lane + 1];
    }
}

// ---------------- output head: LeakyReLU(h @ Wout.T + bout) ----------------
__global__ void out_kernel(const float* h, const float* Wout, const float* bout, float* out) {
    int tid = blockIdx.x * blockDim.x + threadIdx.x;
    int n = tid >> 6, c = tid & 63;
    if (n >= NN) return;
    float acc = bout[c];
    const float* hr = h + (size_t)n * HIDD;
    const float* wr = Wout + c * HIDD;
    #pragma unroll
    for (int k = 0; k < HIDD; k++) acc += hr[k] * wr[k];
    out[tid] = lrelu(acc);
}

extern "C" void kernel_launch(void* const* d_in, const int* in_sizes, int n_in,
                              void* d_out, int out_size, void* d_ws, size_t ws_size,
                              hipStream_t stream) {
    const float* x     = (const float*)d_in[0];
    const int*   ei    = (const int*)  d_in[1];
    const float* eattr = (const float*)d_in[2];
    const float* W0    = (const float*)d_in[3];
    const float* b0    = (const float*)d_in[4];
    const float* bn_g  = (const float*)d_in[5];
    const float* bn_b  = (const float*)d_in[6];
    const float* bn_m  = (const float*)d_in[7];
    const float* bn_v  = (const float*)d_in[8];
    const float* Wl[2]   = { (const float*)d_in[9],  (const float*)d_in[16] };
    const float* bl[2]   = { (const float*)d_in[10], (const float*)d_in[17] };
    const float* Wr[2]   = { (const float*)d_in[11], (const float*)d_in[18] };
    const float* br[2]   = { (const float*)d_in[12], (const float*)d_in[19] };
    const float* We[2]   = { (const float*)d_in[13], (const float*)d_in[20] };
    const float* att[2]  = { (const float*)d_in[14], (const float*)d_in[21] };
    const float* bias[2] = { (const float*)d_in[15], (const float*)d_in[22] };
    const float* Wout  = (const float*)d_in[23];
    const float* bout  = (const float*)d_in[24];
    float* out = (float*)d_out;

    const int Et = EE + NN;
    char* p = (char*)d_ws;
    auto carve = [&](size_t bytes) { char* r = p; p += (bytes + 255) & ~(size_t)255; return r; };
    float* e_feat    = (float*)carve((size_t)NN * HIDD * 4);   // embed out / layer2 out
    float* h1        = (float*)carve((size_t)NN * HIDD * 4);   // layer1 out
    float* xl        = (float*)carve((size_t)NN * HC * 4);
    float* xr        = (float*)carve((size_t)NN * HC * 4);
    float* loop_attr = (float*)carve((size_t)NN * EDD * 4);
    int*   cnt       = (int*)  carve((size_t)NN * 4);
    int*   rowstart  = (int*)  carve((size_t)(NN + 1) * 4);
    int*   cursor    = (int*)  carve((size_t)NN * 4);
    int*   csr_e     = (int*)  carve((size_t)Et * 4);
    int*   csr_src   = (int*)  carve((size_t)Et * 4);

    hipMemsetAsync(cnt, 0, (size_t)NN * 4, stream);
    hipMemsetAsync(cursor, 0, (size_t)NN * 4, stream);
    hipMemsetAsync(loop_attr, 0, (size_t)NN * EDD * 4, stream);

    count_kernel<<<(EE + 255) / 256, 256, 0, stream>>>(ei, cnt);
    loopsum_kernel<<<(EE * EDD + 255) / 256, 256, 0, stream>>>(ei, eattr, loop_attr);
    scan_kernel<<<1, 1024, 0, stream>>>(cnt, rowstart);
    loopdiv_kernel<<<(NN * EDD + 255) / 256, 256, 0, stream>>>(loop_attr, cnt);
    scatter_kernel<<<(EE + 255) / 256, 256, 0, stream>>>(ei, rowstart, cursor, csr_e, csr_src);
    selfloop_kernel<<<(NN + 255) / 256, 256, 0, stream>>>(rowstart, cnt, csr_e, csr_src);

    embed_kernel<<<NN / 8, 256, 0, stream>>>(x, W0, b0, bn_g, bn_b, bn_m, bn_v, e_feat);

    const float* fin[2] = { e_feat, h1 };
    float* fout[2] = { h1, e_feat };   // reuse e_feat as layer-2 output
    for (int l = 0; l < 2; l++) {
        lin_kernel<<<NN / 4, 256, 0, stream>>>(fin[l], Wl[l], bl[l], Wr[l], br[l], xl, xr);
        gat_fused_kernel<<<((size_t)NN * 64 + 255) / 256, 256, 0, stream>>>(
            xl, xr, eattr, loop_attr, We[l], att[l], rowstart, csr_e, csr_src,
            bias[l], fout[l]);
    }
    out_kernel<<<(NN * 64 + 255) / 256, 256, 0, stream>>>(e_feat, Wout, bout, out);
}

// Round 3
// 935.198 us; speedup vs baseline: 2.7341x; 1.3470x over previous
//
#include <hip/hip_runtime.h>
#include <math.h>

#define NN   50000
#define EE   800000
#define IND  128
#define EDD  16
#define HIDD 32
#define NH   4
#define HC   128     // NH*HIDD
#define OUTD 64
#define NEG  0.1f
#define BN_EPS 1e-5f

__device__ __forceinline__ float lrelu(float x) { return x >= 0.f ? x : NEG * x; }

// ---------------- CSR build (real edges only; self-loops handled in fused kernel) ----
__global__ void count_kernel(const int* ei, int* cnt) {
    int e = blockIdx.x * blockDim.x + threadIdx.x;
    if (e >= EE) return;
    atomicAdd(&cnt[ei[EE + e]], 1);
}

// single-block exclusive scan of cnt; rowstart[NN] = E. Wave-shfl based.
__global__ void scan_kernel(const int* cnt, int* rowstart) {
    __shared__ int wsum[16];
    __shared__ int carry_s;
    int tid = threadIdx.x;
    int wid = tid >> 6, lane = tid & 63;
    if (tid == 0) carry_s = 0;
    __syncthreads();
    for (int base = 0; base < NN; base += 1024) {
        int i = base + tid;
        int v = (i < NN) ? cnt[i] : 0;
        int s = v;
        #pragma unroll
        for (int off = 1; off < 64; off <<= 1) {
            int t = __shfl_up(s, off);
            if (lane >= off) s += t;
        }
        if (lane == 63) wsum[wid] = s;
        __syncthreads();
        if (wid == 0) {
            int ws = (lane < 16) ? wsum[lane] : 0;
            #pragma unroll
            for (int off = 1; off < 16; off <<= 1) {
                int t = __shfl_up(ws, off);
                if (lane >= off) ws += t;
            }
            if (lane < 16) wsum[lane] = ws;   // inclusive wave sums
        }
        __syncthreads();
        int wave_off = (wid > 0) ? wsum[wid - 1] : 0;
        int carry = carry_s;
        if (i < NN) rowstart[i] = carry + wave_off + s - v;   // exclusive
        __syncthreads();
        if (tid == 0) carry_s = carry + wsum[15];
        __syncthreads();
    }
    if (threadIdx.x == 0) rowstart[NN] = carry_s;
}

// pack (edge id, src id) into one int2 — one scalar 8B load per edge in the consumer
__global__ void scatter_kernel(const int* ei, const int* rowstart, int* cursor, int2* csr_es) {
    int e = blockIdx.x * blockDim.x + threadIdx.x;
    if (e >= EE) return;
    int d = ei[EE + e];
    int pos = rowstart[d] + atomicAdd(&cursor[d], 1);
    csr_es[pos] = make_int2(e, ei[e]);
}

// ---------------- input embed: Linear(128->32)+BN(eval)+LeakyReLU ----------------
__global__ void embed_kernel(const float* x, const float* W0, const float* b0,
                             const float* g, const float* bb, const float* bm,
                             const float* bv, float* out) {
    int tid = threadIdx.x;
    int c = tid & 31, r = tid >> 5;           // 8 rows x 32 cols per block
    int n0 = blockIdx.x * 8;
    __shared__ float sx[8][IND];
    for (int i = tid; i < 8 * IND; i += 256) sx[i >> 7][i & 127] = x[(size_t)n0 * IND + i];
    __syncthreads();
    float acc = b0[c];
    const float* wr = W0 + c * IND;
    #pragma unroll 8
    for (int k = 0; k < IND; k++) acc += sx[r][k] * wr[k];
    float bn = (acc - bm[c]) * (1.0f / sqrtf(bv[c] + BN_EPS)) * g[c] + bb[c];
    out[(size_t)(n0 + r) * HIDD + c] = lrelu(bn);
}

// ---------------- per-layer linear: xl = f@Wl.T+bl, xr = f@Wr.T+br ----------------
__global__ void lin_kernel(const float* f, const float* Wl, const float* bl,
                           const float* Wr, const float* br, float* xl, float* xr) {
    int j = threadIdx.x;                       // 0..255
    int n0 = blockIdx.x * 4;                   // 4 nodes per block
    const float* W = (j < HC) ? Wl : Wr;
    const float* b = (j < HC) ? bl : br;
    float*       o = (j < HC) ? xl : xr;
    int c = j & (HC - 1);
    __shared__ float sf[4][HIDD];
    if (threadIdx.x < 128) sf[threadIdx.x >> 5][threadIdx.x & 31] =
        f[(size_t)(n0 + (threadIdx.x >> 5)) * HIDD + (threadIdx.x & 31)];
    __syncthreads();
    float bc = b[c];
    float a0 = bc, a1 = bc, a2 = bc, a3 = bc;
    const float* wr = W + c * HIDD;
    #pragma unroll
    for (int k = 0; k < HIDD; k++) {
        float w = wr[k];
        a0 += sf[0][k] * w; a1 += sf[1][k] * w;
        a2 += sf[2][k] * w; a3 += sf[3][k] * w;
    }
    o[(size_t)(n0 + 0) * HC + c] = a0;
    o[(size_t)(n0 + 1) * HC + c] = a1;
    o[(size_t)(n0 + 2) * HC + c] = a2;
    o[(size_t)(n0 + 3) * HC + c] = a3;
}

// per-edge online-softmax update; all 64 lanes active (wave-uniform callers only)
__device__ __forceinline__ void gat_edge_update(
    float2 xv, float ev, float2 xrv, float att0, float att1,
    const float* w0, const float* w1,
    float& mh, float& lh, float& acc0, float& acc1)
{
    float ea0 = 0.f, ea1 = 0.f;
    #pragma unroll
    for (int k = 0; k < EDD; k++) {
        float ek = __shfl(ev, k);
        ea0 += w0[k] * ek;
        ea1 += w1[k] * ek;
    }
    float m0 = lrelu(xv.x + xrv.x + ea0);
    float m1 = lrelu(xv.y + xrv.y + ea1);
    float p = m0 * att0 + m1 * att1;
    p += __shfl_xor(p, 1); p += __shfl_xor(p, 2);
    p += __shfl_xor(p, 4); p += __shfl_xor(p, 8);   // per-head logit (uniform in 16-lane group)
    float newm = fmaxf(mh, p);
    float scale = __expf(mh - newm);                 // first edge: exp(-inf)=0
    float w = __expf(p - newm);
    lh   = lh   * scale + w;
    acc0 = acc0 * scale + w * xv.x;
    acc1 = acc1 * scale + w * xv.y;
    mh = newm;
}

// ---------------- fused: edge scoring + online softmax + aggregate + self-loop ------
// one wave per dst node; lane owns channels (2*lane, 2*lane+1); head = lane>>4
__global__ void gat_fused_kernel(const float* __restrict__ xl, const float* __restrict__ xr,
                                 const float* __restrict__ eattr,
                                 const float* __restrict__ We, const float* __restrict__ att,
                                 const int* __restrict__ rowstart, const int2* __restrict__ csr_es,
                                 const float* __restrict__ bias, float* __restrict__ out) {
    int n = (blockIdx.x * blockDim.x + threadIdx.x) >> 6;
    n = __builtin_amdgcn_readfirstlane(n);          // provably wave-uniform -> scalar loads
    int lane = threadIdx.x & 63;
    if (n >= NN) return;
    int start = rowstart[n], end = rowstart[n + 1];
    int deg = end - start;
    int c0 = 2 * lane;

    float2 xrv = *(const float2*)(xr + (size_t)n * HC + c0);
    float att0 = att[c0], att1 = att[c0 + 1];
    float w0[EDD], w1[EDD];
    #pragma unroll
    for (int k = 0; k < EDD; k++) { w0[k] = We[c0 * EDD + k]; w1[k] = We[(c0 + 1) * EDD + k]; }

    float mh = -INFINITY, lh = 0.f;
    float acc0 = 0.f, acc1 = 0.f;
    float evsum = 0.f;                               // lanes<16: running sum of edge_attr

    float2 xA[4]; float evA[4]; int mA = 0;
    float2 xB[4]; float evB[4];

    // load a chunk of up to 4 edges
    auto loadChunk = [&](int i0, float2* xb, float* evb) -> int {
        int m = end - i0; if (m > 4) m = 4;
        #pragma unroll
        for (int j = 0; j < 4; j++) {
            if (j < m) {
                int2 es = csr_es[i0 + j];            // wave-uniform -> s_load
                xb[j]  = *(const float2*)(xl + (size_t)es.y * HC + c0);
                evb[j] = (lane < EDD) ? eattr[(size_t)es.x * EDD + lane] : 0.f;
            } else { xb[j] = make_float2(0.f, 0.f); evb[j] = 0.f; }
        }
        return m;
    };

    if (deg > 0) mA = loadChunk(start, xA, evA);
    for (int i0 = start; i0 < end; i0 += 4) {
        int mB = 0;
        if (i0 + 4 < end) mB = loadChunk(i0 + 4, xB, evB);   // prefetch next chunk
        #pragma unroll
        for (int j = 0; j < 4; j++) {
            if (j < mA) {
                evsum += evA[j];
                gat_edge_update(xA[j], evA[j], xrv, att0, att1, w0, w1, mh, lh, acc0, acc1);
            }
        }
        mA = mB;
        #pragma unroll
        for (int j = 0; j < 4; j++) { xA[j] = xB[j]; evA[j] = evB[j]; }
    }

    // self-loop: edge_attr = mean of incoming (0 if none), src = n
    float invdeg = 1.0f / (float)(deg > 0 ? deg : 1);
    float evL = evsum * invdeg;
    float2 xL = *(const float2*)(xl + (size_t)n * HC + c0);
    gat_edge_update(xL, evL, xrv, att0, att1, w0, w1, mh, lh, acc0, acc1);

    float inv = 1.0f / lh;
    acc0 *= inv; acc1 *= inv;
    // heads-mean: sum lanes {l, l^16, l^32, l^48}
    acc0 += __shfl_xor(acc0, 16); acc0 += __shfl_xor(acc0, 32);
    acc1 += __shfl_xor(acc1, 16); acc1 += __shfl_xor(acc1, 32);
    if (lane < 16) {
        float2 o = make_float2(acc0 * 0.25f + bias[2 * lane],
                               acc1 * 0.25f + bias[2 * lane + 1]);
        *(float2*)(out + (size_t)n * HIDD + 2 * lane) = o;
    }
}

// ---------------- output head: LeakyReLU(h @ Wout.T + bout) ----------------
__global__ void out_kernel(const float* h, const float* Wout, const float* bout, float* out) {
    int tid = blockIdx.x * blockDim.x + threadIdx.x;
    int n = tid >> 6, c = tid & 63;
    if (n >= NN) return;
    float acc = bout[c];
    const float* hr = h + (size_t)n * HIDD;
    const float* wr = Wout + c * HIDD;
    #pragma unroll
    for (int k = 0; k < HIDD; k++) acc += hr[k] * wr[k];
    out[tid] = lrelu(acc);
}

extern "C" void kernel_launch(void* const* d_in, const int* in_sizes, int n_in,
                              void* d_out, int out_size, void* d_ws, size_t ws_size,
                              hipStream_t stream) {
    const float* x     = (const float*)d_in[0];
    const int*   ei    = (const int*)  d_in[1];
    const float* eattr = (const float*)d_in[2];
    const float* W0    = (const float*)d_in[3];
    const float* b0    = (const float*)d_in[4];
    const float* bn_g  = (const float*)d_in[5];
    const float* bn_b  = (const float*)d_in[6];
    const float* bn_m  = (const float*)d_in[7];
    const float* bn_v  = (const float*)d_in[8];
    const float* Wl[2]   = { (const float*)d_in[9],  (const float*)d_in[16] };
    const float* bl[2]   = { (const float*)d_in[10], (const float*)d_in[17] };
    const float* Wr[2]   = { (const float*)d_in[11], (const float*)d_in[18] };
    const float* br[2]   = { (const float*)d_in[12], (const float*)d_in[19] };
    const float* We[2]   = { (const float*)d_in[13], (const float*)d_in[20] };
    const float* att[2]  = { (const float*)d_in[14], (const float*)d_in[21] };
    const float* bias[2] = { (const float*)d_in[15], (const float*)d_in[22] };
    const float* Wout  = (const float*)d_in[23];
    const float* bout  = (const float*)d_in[24];
    float* out = (float*)d_out;

    char* p = (char*)d_ws;
    auto carve = [&](size_t bytes) { char* r = p; p += (bytes + 255) & ~(size_t)255; return r; };
    float* e_feat    = (float*)carve((size_t)NN * HIDD * 4);   // embed out / layer2 out
    float* h1        = (float*)carve((size_t)NN * HIDD * 4);   // layer1 out
    float* xl        = (float*)carve((size_t)NN * HC * 4);
    float* xr        = (float*)carve((size_t)NN * HC * 4);
    int*   cnt       = (int*)  carve((size_t)NN * 4);
    int*   rowstart  = (int*)  carve((size_t)(NN + 1) * 4);
    int*   cursor    = (int*)  carve((size_t)NN * 4);
    int2*  csr_es    = (int2*) carve((size_t)EE * 8);

    hipMemsetAsync(cnt, 0, (size_t)NN * 4, stream);
    hipMemsetAsync(cursor, 0, (size_t)NN * 4, stream);

    count_kernel<<<(EE + 255) / 256, 256, 0, stream>>>(ei, cnt);
    scan_kernel<<<1, 1024, 0, stream>>>(cnt, rowstart);
    scatter_kernel<<<(EE + 255) / 256, 256, 0, stream>>>(ei, rowstart, cursor, csr_es);

    embed_kernel<<<NN / 8, 256, 0, stream>>>(x, W0, b0, bn_g, bn_b, bn_m, bn_v, e_feat);

    const float* fin[2] = { e_feat, h1 };
    float* fout[2] = { h1, e_feat };   // reuse e_feat as layer-2 output
    for (int l = 0; l < 2; l++) {
        lin_kernel<<<NN / 4, 256, 0, stream>>>(fin[l], Wl[l], bl[l], Wr[l], br[l], xl, xr);
        gat_fused_kernel<<<((size_t)NN * 64 + 255) / 256, 256, 0, stream>>>(
            xl, xr, eattr, We[l], att[l], rowstart, csr_es, bias[l], fout[l]);
    }
    out_kernel<<<(NN * 64 + 255) / 256, 256, 0, stream>>>(e_feat, Wout, bout, out);
}